// Round 1
// baseline (990.863 us; speedup 1.0000x reference)
//
#include <hip/hip_runtime.h>
#include <cstdint>
#include <cstddef>

// Problem constants
#define B_SZ  8192
#define IN_SZ 2048
#define H_SZ  2048
#define KC_SZ 4096   // IN + H

typedef unsigned short ushort_t;
typedef __attribute__((ext_vector_type(8))) short bf16x8;   // 8 bf16 = 4 VGPRs
typedef __attribute__((ext_vector_type(4))) float floatx4;  // MFMA C/D

__device__ __forceinline__ ushort_t f2bf(float f) {
  union { float f; unsigned u; } v; v.f = f;
  unsigned u = v.u;
  return (ushort_t)((u + 0x7FFFu + ((u >> 16) & 1u)) >> 16);  // RNE
}

__device__ __forceinline__ void g2lds16(const void* g, void* l) {
  __builtin_amdgcn_global_load_lds(
      (const __attribute__((address_space(1))) unsigned int*)g,
      (__attribute__((address_space(3))) unsigned int*)l, 16, 0, 0);
}

// ---------------------------------------------------------------------------
// prep: concat_input (fp32, exact) + bf16 A into workspace. One float4/thread.
__global__ void prep_concat(const float* __restrict__ in, const float* __restrict__ st,
                            float* __restrict__ cat, ushort_t* __restrict__ Abf) {
  size_t i4 = (size_t)blockIdx.x * blockDim.x + threadIdx.x;  // over B*KC/4
  size_t row  = i4 >> 10;        // / (KC/4)
  size_t col4 = i4 & 1023;
  float4 v;
  if (col4 < (IN_SZ / 4))
    v = ((const float4*)in)[row * (IN_SZ / 4) + col4];
  else
    v = ((const float4*)st)[row * (H_SZ / 4) + (col4 - IN_SZ / 4)];
  ((float4*)cat)[i4] = v;
  union { ushort_t u[4]; uint2 p; } pk;
  pk.u[0] = f2bf(v.x); pk.u[1] = f2bf(v.y); pk.u[2] = f2bf(v.z); pk.u[3] = f2bf(v.w);
  ((uint2*)Abf)[i4] = pk.p;
}

// bf16 casts of gate_weights [H,KC] and weights_i [H,IN]
__global__ void prep_weights(const float* __restrict__ gw, const float* __restrict__ wi,
                             ushort_t* __restrict__ Wg, ushort_t* __restrict__ Wi) {
  size_t i4 = (size_t)blockIdx.x * blockDim.x + threadIdx.x;
  const size_t n1 = (size_t)H_SZ * KC_SZ / 4;
  union { ushort_t u[4]; uint2 p; } pk;
  if (i4 < n1) {
    float4 v = ((const float4*)gw)[i4];
    pk.u[0] = f2bf(v.x); pk.u[1] = f2bf(v.y); pk.u[2] = f2bf(v.z); pk.u[3] = f2bf(v.w);
    ((uint2*)Wg)[i4] = pk.p;
  } else {
    size_t j = i4 - n1;
    float4 v = ((const float4*)wi)[j];
    pk.u[0] = f2bf(v.x); pk.u[1] = f2bf(v.y); pk.u[2] = f2bf(v.z); pk.u[3] = f2bf(v.w);
    ((uint2*)Wi)[j] = pk.p;
  }
}

// ---------------------------------------------------------------------------
// m97-style bf16 GEMM, C = A (row-major, lda) x W^T (row-major, ldw), N = H_SZ.
// BM=BN=128, BK=64, 256 threads = 4 waves, each wave 64x64 via 4x4 16x16x32 MFMA.
// EPI=0: gate epilogue  (o0=pre_gate, o1=gate, x0=bias)
// EPI=1: value epilogue (o0=values, o1=pre_h, o2=new_h, x0=gate, x1=state)
template <int EPI>
__global__ __launch_bounds__(256) void gemm_bt(
    const ushort_t* __restrict__ A, const ushort_t* __restrict__ W,
    int K, int lda, int ldw,
    float* __restrict__ o0, float* __restrict__ o1, float* __restrict__ o2,
    const float* __restrict__ x0, const float* __restrict__ x1) {
  constexpr int BM = 128, BN = 128, BK = 64;
  __shared__ __align__(16) ushort_t sA[BM * BK];
  __shared__ __align__(16) ushort_t sB[BN * BK];

  const int tid  = threadIdx.x;
  const int lane = tid & 63;
  const int quad = lane >> 4;
  const int l16  = lane & 15;
  const int wm = ((tid >> 6) >> 1) * 64;   // wave row offset in tile
  const int wn = ((tid >> 6) & 1) * 64;    // wave col offset in tile

  const int nTiles = H_SZ / BN;            // 16
  const int row0 = (blockIdx.x / nTiles) * BM;
  const int col0 = (blockIdx.x % nTiles) * BN;

  floatx4 acc[4][4] = {};

  const ushort_t* Ab = A + (size_t)row0 * lda;
  const ushort_t* Wb = W + (size_t)col0 * ldw;
  const int ldsbase = (tid & 192) * 8;     // wave-uniform: wave*64 chunks * 8 elems

  for (int k0 = 0; k0 < K; k0 += BK) {
#pragma unroll
    for (int it = 0; it < 4; ++it) {       // 128x64 bf16 tile = 1024 16B chunks
      int chunk = it * 256 + tid;
      int r = chunk >> 3;
      int c = (chunk & 7) << 3;
      g2lds16(Ab + (size_t)r * lda + (k0 + c), &sA[it * 2048 + ldsbase]);
    }
#pragma unroll
    for (int it = 0; it < 4; ++it) {
      int chunk = it * 256 + tid;
      int r = chunk >> 3;
      int c = (chunk & 7) << 3;
      g2lds16(Wb + (size_t)r * ldw + (k0 + c), &sB[it * 2048 + ldsbase]);
    }
    __syncthreads();
#pragma unroll
    for (int ks = 0; ks < BK; ks += 32) {
      bf16x8 af[4], bfr[4];
#pragma unroll
      for (int i = 0; i < 4; ++i)
        af[i] = *(const bf16x8*)&sA[(wm + i * 16 + l16) * BK + ks + quad * 8];
#pragma unroll
      for (int j = 0; j < 4; ++j)
        bfr[j] = *(const bf16x8*)&sB[(wn + j * 16 + l16) * BK + ks + quad * 8];
#pragma unroll
      for (int i = 0; i < 4; ++i)
#pragma unroll
        for (int j = 0; j < 4; ++j)
          acc[i][j] = __builtin_amdgcn_mfma_f32_16x16x32_bf16(af[i], bfr[j], acc[i][j], 0, 0, 0);
    }
    __syncthreads();
  }

  // Epilogue. C/D layout: col = lane&15, row = quad*4 + reg (m89-verified).
  if (EPI == 0) {
    float bj[4];
#pragma unroll
    for (int j = 0; j < 4; ++j) bj[j] = x0[col0 + wn + j * 16 + l16];
#pragma unroll
    for (int i = 0; i < 4; ++i) {
      int rbase = row0 + wm + i * 16 + quad * 4;
#pragma unroll
      for (int j = 0; j < 4; ++j) {
        int col = col0 + wn + j * 16 + l16;
#pragma unroll
        for (int r = 0; r < 4; ++r) {
          size_t idx = (size_t)(rbase + r) * H_SZ + col;
          float pre = acc[i][j][r] + bj[j];
          o0[idx] = pre;
          o1[idx] = fminf(fmaxf(pre, 0.f), 1.f);
        }
      }
    }
  } else {
#pragma unroll
    for (int i = 0; i < 4; ++i) {
      int rbase = row0 + wm + i * 16 + quad * 4;
#pragma unroll
      for (int j = 0; j < 4; ++j) {
        int col = col0 + wn + j * 16 + l16;
#pragma unroll
        for (int r = 0; r < 4; ++r) {
          size_t idx = (size_t)(rbase + r) * H_SZ + col;
          float v  = tanhf(acc[i][j][r]);
          float g  = x0[idx];
          float s  = x1[idx];
          float ph = s * (1.f - g) + v * g;
          o0[idx] = v;
          o1[idx] = ph;
          o2[idx] = fmaxf(ph, 0.f);
        }
      }
    }
  }
}

// ---------------------------------------------------------------------------
// Fallback (only if ws_size < 88 MiB): naive fp32, correct but slow.
__global__ void concat_only(const float* __restrict__ in, const float* __restrict__ st,
                            float* __restrict__ cat) {
  size_t i4 = (size_t)blockIdx.x * blockDim.x + threadIdx.x;
  size_t row = i4 >> 10, col4 = i4 & 1023;
  float4 v;
  if (col4 < (IN_SZ / 4))
    v = ((const float4*)in)[row * (IN_SZ / 4) + col4];
  else
    v = ((const float4*)st)[row * (H_SZ / 4) + (col4 - IN_SZ / 4)];
  ((float4*)cat)[i4] = v;
}

__global__ void naive_all(const float* __restrict__ in, const float* __restrict__ st,
                          const float* __restrict__ gw, const float* __restrict__ gb,
                          const float* __restrict__ wi,
                          float* __restrict__ new_h, float* __restrict__ pre_gate,
                          float* __restrict__ gate, float* __restrict__ values,
                          float* __restrict__ pre_h) {
  size_t idx = (size_t)blockIdx.x * blockDim.x + threadIdx.x;
  if (idx >= (size_t)B_SZ * H_SZ) return;
  int b = (int)(idx / H_SZ), h = (int)(idx % H_SZ);
  const float* wgr = gw + (size_t)h * KC_SZ;
  const float* wir = wi + (size_t)h * IN_SZ;
  const float* x = in + (size_t)b * IN_SZ;
  const float* s = st + (size_t)b * H_SZ;
  float ag = 0.f, av = 0.f;
  for (int c = 0; c < IN_SZ; ++c) { float a = x[c]; ag += a * wgr[c]; av += a * wir[c]; }
  for (int c = 0; c < H_SZ; ++c) ag += s[c] * wgr[IN_SZ + c];
  float pre = ag + gb[h];
  float g = fminf(fmaxf(pre, 0.f), 1.f);
  float v = tanhf(av);
  float ph = s[h] * (1.f - g) + v * g;
  pre_gate[idx] = pre; gate[idx] = g; values[idx] = v;
  pre_h[idx] = ph; new_h[idx] = fmaxf(ph, 0.f);
}

// ---------------------------------------------------------------------------
extern "C" void kernel_launch(void* const* d_in, const int* in_sizes, int n_in,
                              void* d_out, int out_size, void* d_ws, size_t ws_size,
                              hipStream_t stream) {
  const float* input = (const float*)d_in[0];
  const float* state = (const float*)d_in[1];
  const float* gw    = (const float*)d_in[2];
  const float* gb    = (const float*)d_in[3];
  const float* wi    = (const float*)d_in[4];

  float* out      = (float*)d_out;
  float* new_h    = out;                                   // [B,H]
  float* cat      = new_h + (size_t)B_SZ * H_SZ;           // [B,KC]
  float* pre_gate = cat + (size_t)B_SZ * KC_SZ;            // [B,H]
  float* gate     = pre_gate + (size_t)B_SZ * H_SZ;        // [B,H]
  float* values   = gate + (size_t)B_SZ * H_SZ;            // [B,H]
  float* pre_h    = values + (size_t)B_SZ * H_SZ;          // [B,H]

  const size_t needA  = (size_t)B_SZ * KC_SZ * 2;   // 64 MiB
  const size_t needWg = (size_t)H_SZ * KC_SZ * 2;   // 16 MiB
  const size_t needWi = (size_t)H_SZ * IN_SZ * 2;   //  8 MiB
  if (ws_size >= needA + needWg + needWi) {
    ushort_t* Abf  = (ushort_t*)d_ws;
    ushort_t* Wgbf = Abf + (size_t)B_SZ * KC_SZ;
    ushort_t* Wibf = Wgbf + (size_t)H_SZ * KC_SZ;

    prep_concat<<<dim3((B_SZ * (size_t)KC_SZ / 4) / 256), dim3(256), 0, stream>>>(
        input, state, cat, Abf);
    prep_weights<<<dim3(((size_t)H_SZ * KC_SZ / 4 + (size_t)H_SZ * IN_SZ / 4) / 256),
                   dim3(256), 0, stream>>>(gw, wi, Wgbf, Wibf);

    const int grid = (B_SZ / 128) * (H_SZ / 128);  // 64 * 16 = 1024
    gemm_bt<0><<<dim3(grid), dim3(256), 0, stream>>>(
        Abf, Wgbf, KC_SZ, KC_SZ, KC_SZ, pre_gate, gate, nullptr, gb, nullptr);
    gemm_bt<1><<<dim3(grid), dim3(256), 0, stream>>>(
        Abf, Wibf, IN_SZ, KC_SZ, IN_SZ, values, pre_h, new_h, gate, state);
  } else {
    concat_only<<<dim3((B_SZ * (size_t)KC_SZ / 4) / 256), dim3(256), 0, stream>>>(
        input, state, cat);
    naive_all<<<dim3((B_SZ * (size_t)H_SZ + 255) / 256), dim3(256), 0, stream>>>(
        input, state, gw, gb, wi, new_h, pre_gate, gate, values, pre_h);
  }
}